// Round 7
// baseline (1433.479 us; speedup 1.0000x reference)
//
#include <hip/hip_runtime.h>
#include <hip/hip_bf16.h>

// RCNN: bidirectional simple-RNN + conv1x1 + global max pool + dense sigmoid
// B=256 T=512 V=50000 E=128 H=256 C=128
//
// Round-21 = R19 (best verified: 546 total / 462 fused) + 2 blocks/CU.
// R16-R20 established the RNN step (~2060 cyc) is ~60% exposed latency (S):
// barrier drains + first-use LDS/MFMA/tanh tails, hidable only by
// co-resident independent work -- which the 120KB dynamic-LDS allocation
// (1 block/CU) made impossible. R21:
//  - convpool tile single-buffered: dynamic LDS 82,944 -> 41,472 B. Per
//    block 17,920 static + 41,472 dynamic = 59,392 B -> 2 blocks/CU.
//    Convpool pays +1 barrier per t-pair (off critical path).
//  - __launch_bounds__(512, 4): 4 waves/SIMD; R19 compiled at 96 VGPR, well
//    under the 128 cap, so no spill.
//  - every RNN chain now shares its CU with another block (RNN sibling or
//    producer); per-step S hides under the partner's issue stream (m114:
//    MFMA/VALU/LDS co-schedule across blocks).
//  - RNN body / producers / prep / dense: verbatim R19 (lagged publish,
//    flag acquire-prefetch, split accumulators, sc1 stores).

#define B_ 256
#define T_ 512
#define E_ 128
#define H_ 256
#define C_ 128

typedef __attribute__((ext_vector_type(8))) short short8;
typedef __attribute__((ext_vector_type(4))) float float4v;
typedef __attribute__((ext_vector_type(2))) unsigned int uint2v;

__device__ inline unsigned short f2bf(float f) {
  unsigned u = __float_as_uint(f);
  u += 0x7fffu + ((u >> 16) & 1u);  // RNE
  return (unsigned short)(u >> 16);
}
__device__ inline unsigned pkbf(float a, float b) {
  __hip_bfloat162 h2 = __float22bfloat162_rn(float2{a, b});
  union { __hip_bfloat162 h; unsigned u; } cv;
  cv.h = h2;
  return cv.u;
}
__device__ inline float lo16f(unsigned u) { return __uint_as_float(u << 16); }
__device__ inline float hi16f(unsigned u) { return __uint_as_float(u & 0xffff0000u); }
__device__ inline float fast_tanh(float x) {
  float e = __expf(2.f * x);                 // inf ok -> 1
  float r = __builtin_amdgcn_rcpf(e + 1.f);
  return __builtin_fmaf(-2.f, r, 1.f);
}
__device__ inline unsigned enc_f(float f) {
  unsigned u = __float_as_uint(f);
  return (u & 0x80000000u) ? ~u : (u | 0x80000000u);
}
__device__ inline float dec_f(unsigned key) {
  unsigned bits = (key & 0x80000000u) ? (key ^ 0x80000000u) : ~key;
  return __uint_as_float(bits);
}
__device__ inline void sync_lds() {
  asm volatile("s_waitcnt lgkmcnt(0)\n\ts_barrier" ::: "memory");
}

// 8-byte store coherent at agent scope (sc1: bypasses XCD L2, lands at the
// chip coherence point). vmcnt(0) after these == globally visible.
__device__ inline void st_agent(unsigned short* p, uint2v v) {
  union { uint2v v2; unsigned long long u; } cv;
  cv.v2 = v;
  __hip_atomic_store(reinterpret_cast<unsigned long long*>(p), cv.u,
                     __ATOMIC_RELAXED, __HIP_MEMORY_SCOPE_AGENT);
}

// spin until *f >= v (flags go 0 -> 1 (xw ready) -> 2 (h ready)), then one
// acquire load to invalidate this XCD's caches.
__device__ inline void wait_flag_ge(const int* f, int v) {
  if (__hip_atomic_load(f, __ATOMIC_RELAXED, __HIP_MEMORY_SCOPE_AGENT) < v) {
    while (__hip_atomic_load(f, __ATOMIC_RELAXED, __HIP_MEMORY_SCOPE_AGENT) <
           v)
      __builtin_amdgcn_s_sleep(8);
  }
  (void)__hip_atomic_load(f, __ATOMIC_ACQUIRE, __HIP_MEMORY_SCOPE_AGENT);
}

// ---------------------------------------------------------------------------
// prep: WfT/WbT:[256][128] WcT:[128][640] UfT/UbT:[256][256] (all [n][k]).
// Output-indexed loops: coalesced writes, strided reads (L1 line reuse).
// ---------------------------------------------------------------------------
__global__ __launch_bounds__(256) void prep_kernel(
    const float* __restrict__ Wf, const float* __restrict__ Wb,
    const float* __restrict__ Wc, const float* __restrict__ Uf,
    const float* __restrict__ Ub,
    unsigned short* __restrict__ WfT, unsigned short* __restrict__ WbT,
    unsigned short* __restrict__ WcT, unsigned short* __restrict__ UfT,
    unsigned short* __restrict__ UbT, unsigned int* __restrict__ pooled,
    int* __restrict__ flags) {
  int gid = blockIdx.x * 256 + threadIdx.x;
  int stride = gridDim.x * 256;
  for (int i = gid; i < 256 * 128; i += stride) {  // WfT/WbT [256][128]
    int n = i >> 7, k = i & 127;
    WfT[i] = f2bf(Wf[k * 256 + n]);
    WbT[i] = f2bf(Wb[k * 256 + n]);
  }
  for (int i = gid; i < 128 * 640; i += stride) {  // WcT [128][640]
    int n = i / 640, k = i - n * 640;
    WcT[i] = f2bf(Wc[k * 128 + n]);
  }
  for (int i = gid; i < 256 * 256; i += stride) {  // UfT/UbT [256][256]
    int n = i >> 8, k = i & 255;
    UfT[i] = f2bf(Uf[k * 256 + n]);
    UbT[i] = f2bf(Ub[k * 256 + n]);
  }
  for (int i = gid; i < B_ * C_; i += stride) pooled[i] = 0u;
  for (int i = gid; i < 1024; i += stride) flags[i] = 0;
}

// ---------------------------------------------------------------------------
// fused: rnn (blocks 0-31) + embxw producers (32-1055) + convpool (1056-1183).
// 59,392 B LDS per block (17,920 static + 41,472 dynamic) -> 2 blocks/CU.
// ---------------------------------------------------------------------------
__global__ __launch_bounds__(512, 4) void fused_kernel(
    const int* __restrict__ idxL, const int* __restrict__ idxR,
    const int* __restrict__ idxC, const float* __restrict__ emb,
    const unsigned short* __restrict__ WfT,
    const unsigned short* __restrict__ WbT,
    const float* __restrict__ bfv, const float* __restrict__ bbv,
    const unsigned short* __restrict__ UfT,
    const unsigned short* __restrict__ UbT,
    const unsigned short* __restrict__ WcT, const float* __restrict__ bc,
    unsigned short* x, unsigned int* __restrict__ pooled,
    int* __restrict__ flags) {
  const int blk = blockIdx.x;
  const int tid = threadIdx.x;
  const int lane = tid & 63, q = lane >> 4, l15 = lane & 15;

  __shared__ __attribute__((aligned(16))) unsigned short hbuf[2][16][280];

  if (blk < 32) {
    // ======================= RNN (R19 body, verbatim) ======================
    const int dir = blk & 1;
    const int btile = blk >> 1;
    const int b0 = btile * 16;
    const unsigned short* __restrict__ UT = dir ? UbT : UfT;
    const int xoff = dir ? 384 : 0;
    const int tstep = dir ? -1 : 1;
    const int t0 = dir ? (T_ - 1) : 0;
    const ptrdiff_t dstep = (ptrdiff_t)tstep * 640;
    const int wv = tid >> 6;
    int* fl = flags + (dir * 16 + btile) * 32;

    unsigned short* hb0 = &hbuf[0][0][0];
    unsigned short* hb1 = &hbuf[1][0][0];
    for (int i = tid; i < 16 * 280; i += 512) hb0[i] = 0;

    short8 ufr[2][8];
#pragma unroll
    for (int mt = 0; mt < 2; ++mt)
#pragma unroll
      for (int kt = 0; kt < 8; ++kt)
        ufr[mt][kt] = *(const short8*)(UT + (32 * wv + 16 * mt + l15) * H_ +
                                       kt * 32 + q * 8);

    int lastc = dir ? 31 : 0;
    wait_flag_ge(fl + lastc, 1);  // covers prologue reads t0..t0+3
    // acquire-prefetch of the NEXT chunk's flag (consumed >=8 iters later;
    // on hit the acquire already ordered subsequent loads -> no fence).
    int fpre = __hip_atomic_load(fl + (dir ? 30 : 1), __ATOMIC_ACQUIRE,
                                 __HIP_MEMORY_SCOPE_AGENT);
    int pending = -1;  // h-chunk awaiting (lagged) publish

    unsigned short* ptrS[2];
    const unsigned short* ptrL[2];
    uint2v curA[2], curB[2], infA[2], infB[2];
#pragma unroll
    for (int mt = 0; mt < 2; ++mt) {
      unsigned short* base =
          x + (size_t)(b0 + 2 * wv + mt) * T_ * 640 + xoff + lane * 4;
      unsigned short* bt = base + (ptrdiff_t)t0 * 640;
      curA[mt] = *(const uint2v*)(bt);
      curB[mt] = *(const uint2v*)(bt + dstep);
      infA[mt] = *(const uint2v*)(bt + 2 * dstep);
      infB[mt] = *(const uint2v*)(bt + 3 * dstep);
      ptrS[mt] = bt;
      ptrL[mt] = bt + 4 * dstep;
    }

    const unsigned lrd = l15 * 280;
    const unsigned lwr = l15 * 280 + 32 * wv;

    __syncthreads();

#pragma unroll 1
    for (int p = 0; p < 256; ++p) {
      // flag for the chunk the prefetch (t +4/+5) touches
      int c = dir ? ((506 - 2 * p) >> 4) : ((2 * p + 5) >> 4);
      c = c < 0 ? 0 : (c > 31 ? 31 : c);
      if (c != lastc) {
        if (fpre < 1) wait_flag_ge(fl + c, 1);
        lastc = c;
        const int nc = c + (dir ? -1 : 1);
        fpre = (nc >= 0 && nc < 32)
                   ? __hip_atomic_load(fl + nc, __ATOMIC_ACQUIRE,
                                       __HIP_MEMORY_SCOPE_AGENT)
                   : 1;
      }
      uint2v ldA[2], ldB[2];
      if (p < 254) {
#pragma unroll
        for (int mt = 0; mt < 2; ++mt) {
          ldA[mt] = *(const uint2v*)(ptrL[mt]);
          ldB[mt] = *(const uint2v*)(ptrL[mt] + dstep);
        }
      } else {
#pragma unroll
        for (int mt = 0; mt < 2; ++mt) {
          ldA[mt] = infA[mt];
          ldB[mt] = infB[mt];
        }
      }
#pragma unroll
      for (int mt = 0; mt < 2; ++mt) ptrL[mt] += 2 * dstep;

      // ---- STEP A: read hb0, write hb1 ----
      {
        short8 afr[8];
#pragma unroll
        for (int kt = 0; kt < 8; ++kt)
          afr[kt] = *(const short8*)(hb0 + lrd + kt * 32 + q * 8);
        float4v accA[2], accB[2];
#pragma unroll
        for (int mt = 0; mt < 2; ++mt) {
          accA[mt] = (float4v){lo16f(curA[mt].x), hi16f(curA[mt].x),
                               lo16f(curA[mt].y), hi16f(curA[mt].y)};
          accB[mt] = (float4v){0.f, 0.f, 0.f, 0.f};
        }
#pragma unroll
        for (int kt = 0; kt < 4; ++kt)
#pragma unroll
          for (int mt = 0; mt < 2; ++mt) {
            accA[mt] = __builtin_amdgcn_mfma_f32_16x16x32_bf16(
                ufr[mt][kt], afr[kt], accA[mt], 0, 0, 0);
            accB[mt] = __builtin_amdgcn_mfma_f32_16x16x32_bf16(
                ufr[mt][kt + 4], afr[kt + 4], accB[mt], 0, 0, 0);
          }
#pragma unroll
        for (int mt = 0; mt < 2; ++mt) {
          float4v s = accA[mt] + accB[mt];
          uint2v hv = {pkbf(fast_tanh(s[0]), fast_tanh(s[1])),
                       pkbf(fast_tanh(s[2]), fast_tanh(s[3]))};
          *(uint2v*)(hb1 + lwr + 16 * mt + 4 * q) = hv;
          st_agent(ptrS[mt], hv);
        }
      }
      sync_lds();

      // ---- STEP B: read hb1, write hb0 ----
      {
        short8 afr[8];
#pragma unroll
        for (int kt = 0; kt < 8; ++kt)
          afr[kt] = *(const short8*)(hb1 + lrd + kt * 32 + q * 8);
        float4v accA[2], accB[2];
#pragma unroll
        for (int mt = 0; mt < 2; ++mt) {
          accA[mt] = (float4v){lo16f(curB[mt].x), hi16f(curB[mt].x),
                               lo16f(curB[mt].y), hi16f(curB[mt].y)};
          accB[mt] = (float4v){0.f, 0.f, 0.f, 0.f};
        }
#pragma unroll
        for (int kt = 0; kt < 4; ++kt)
#pragma unroll
          for (int mt = 0; mt < 2; ++mt) {
            accA[mt] = __builtin_amdgcn_mfma_f32_16x16x32_bf16(
                ufr[mt][kt], afr[kt], accA[mt], 0, 0, 0);
            accB[mt] = __builtin_amdgcn_mfma_f32_16x16x32_bf16(
                ufr[mt][kt + 4], afr[kt + 4], accB[mt], 0, 0, 0);
          }
#pragma unroll
        for (int mt = 0; mt < 2; ++mt) {
          float4v s = accA[mt] + accB[mt];
          uint2v hv = {pkbf(fast_tanh(s[0]), fast_tanh(s[1])),
                       pkbf(fast_tanh(s[2]), fast_tanh(s[3]))};
          *(uint2v*)(hb0 + lwr + 16 * mt + 4 * q) = hv;
          st_agent(ptrS[mt] + dstep, hv);
        }
      }
#pragma unroll
      for (int mt = 0; mt < 2; ++mt) {
        ptrS[mt] += 2 * dstep;
        curA[mt] = infA[mt];
        curB[mt] = infB[mt];
        infA[mt] = ldA[mt];
        infB[mt] = ldB[mt];
      }
      if (((p + 1) & 7) == 0) {
        // lagged publish: vmcnt(16) proves everything older than the newest
        // 16 mem-ops completed -- the PREVIOUS chunk's stores are >=64
        // mem-ops old, so publishing it needs no drain.
        asm volatile("s_waitcnt vmcnt(16) lgkmcnt(0)\n\ts_barrier" :::
                         "memory");
        if (tid == 0 && pending >= 0)
          __hip_atomic_store(fl + pending, 2, __ATOMIC_RELAXED,
                             __HIP_MEMORY_SCOPE_AGENT);
        pending = dir ? (32 - ((p + 1) >> 3)) : (((p + 1) >> 3) - 1);
      } else {
        sync_lds();
      }
    }
    // drain all h-stores, then publish the final pending chunk.
    asm volatile("s_waitcnt vmcnt(0)" ::: "memory");
    __syncthreads();
    if (tid == 0)
      __hip_atomic_store(fl + pending, 2, __ATOMIC_RELAXED,
                         __HIP_MEMORY_SCOPE_AGENT);
    return;
  }

  if (blk < 1056) {
    // ==================== embxw GEMM producer ====================
    const int b2 = blk - 32;
    const int z = b2 >> 5, r = b2 & 31;
    const int btile = r & 15, dirg = r >> 4;
    const int chunk = dirg ? (31 - z) : z;
    const int w8 = tid >> 6;           // 0..7
    const int g = w8 >> 2, wv = w8 & 3;
    const int t0 = chunk * 16 + g * 8;  // this wave-group's 8 t
    const int b0 = btile * 16;
    const int* __restrict__ idx = dirg ? idxR : idxL;
    const unsigned short* __restrict__ WT = dirg ? WbT : WfT;
    const float* __restrict__ bias = dirg ? bbv : bfv;

    short8 wfr[4][4];
#pragma unroll
    for (int mt = 0; mt < 4; ++mt)
#pragma unroll
      for (int kt = 0; kt < 4; ++kt)
        wfr[mt][kt] = *(const short8*)(WT + (64 * wv + 16 * mt + l15) * 128 +
                                       kt * 32 + q * 8);
    float4v bv[4];
#pragma unroll
    for (int mt = 0; mt < 4; ++mt)
      bv[mt] = *(const float4v*)(bias + 64 * wv + 16 * mt + 4 * q);

    int er[8];
#pragma unroll
    for (int j = 0; j < 8; ++j) er[j] = idx[(b0 + l15) * T_ + t0 + j];

    float4v g0[8];
#pragma unroll
    for (int kt = 0; kt < 4; ++kt) {
      const float* p8 = emb + (size_t)er[0] * E_ + kt * 32 + q * 8;
      g0[2 * kt] = *(const float4v*)p8;
      g0[2 * kt + 1] = *(const float4v*)(p8 + 4);
    }

#pragma unroll 1
    for (int j = 0; j < 8; ++j) {
      float4v gn[8];
      if (j < 7) {
#pragma unroll
        for (int kt = 0; kt < 4; ++kt) {
          const float* p8 = emb + (size_t)er[j + 1] * E_ + kt * 32 + q * 8;
          gn[2 * kt] = *(const float4v*)p8;
          gn[2 * kt + 1] = *(const float4v*)(p8 + 4);
        }
      }
      short8 efr[4];
#pragma unroll
      for (int kt = 0; kt < 4; ++kt) {
        union { unsigned u[4]; short8 s; } cv;
        cv.u[0] = pkbf(g0[2 * kt][0], g0[2 * kt][1]);
        cv.u[1] = pkbf(g0[2 * kt][2], g0[2 * kt][3]);
        cv.u[2] = pkbf(g0[2 * kt + 1][0], g0[2 * kt + 1][1]);
        cv.u[3] = pkbf(g0[2 * kt + 1][2], g0[2 * kt + 1][3]);
        efr[kt] = cv.s;
      }
      float4v acc[4];
#pragma unroll
      for (int mt = 0; mt < 4; ++mt) acc[mt] = (float4v){0.f, 0.f, 0.f, 0.f};
#pragma unroll
      for (int kt = 0; kt < 4; ++kt)
#pragma unroll
        for (int mt = 0; mt < 4; ++mt)
          acc[mt] = __builtin_amdgcn_mfma_f32_16x16x32_bf16(
              wfr[mt][kt], efr[kt], acc[mt], 0, 0, 0);
      const int t = t0 + j;
#pragma unroll
      for (int mt = 0; mt < 4; ++mt) {
        float4v v = acc[mt] + bv[mt];
        uint2v pk = {pkbf(v[0], v[1]), pkbf(v[2], v[3])};
        st_agent(x + ((size_t)(b0 + 4 * wv + mt) * T_ + t) * 640 +
                     dirg * 384 + lane * 4,
                 pk);
      }
      if (j < 7) {
#pragma unroll
        for (int kk = 0; kk < 8; ++kk) g0[kk] = gn[kk];
      }
    }
    __syncthreads();  // drains all waves' sc1 stores (vmcnt(0) before barrier)
    if (tid == 0) {
      __hip_atomic_store(flags + (dirg * 16 + btile) * 32 + chunk, 1,
                         __ATOMIC_RELAXED, __HIP_MEMORY_SCOPE_AGENT);
    }
    return;
  }

  // =================== convpool consumer (blocks 1056-1183) =================
  {
    extern __shared__ unsigned short dtile[];  // [2][16][648] = 41,472 B
    const int b2 = blk - 1056;                 // 0..127
    const int btile = b2 & 15, g = b2 >> 4;    // rank-group 0..7
    const int b0 = btile * 16;
    const int w = tid >> 6;                    // wave 0..7 -> cols [16w,16w+16)

    short8 wfr[20];
#pragma unroll
    for (int kt = 0; kt < 20; ++kt)
      wfr[kt] =
          *(const short8*)(WcT + (size_t)(16 * w + l15) * 640 + kt * 32 + q * 8);
    float4v bv = *(const float4v*)(bc + 16 * w + 4 * q);

    float4v mx = (float4v){-1e30f, -1e30f, -1e30f, -1e30f};

    const int* flF = flags + btile * 32;         // fwd  (dir=0)
    const int* flB = flags + (16 + btile) * 32;  // bwd  (dir=1)

    const int srow = tid >> 4;                   // 0..31
    const int tt0 = srow >> 4, row0 = srow & 15;
    const int ssub = tid & 15;
    const int f0 = 16 * (row0 & 7) + 8 * (row0 >> 3);  // e_cur feature base

#pragma unroll 1
    for (int s = 0; s < 4; ++s) {
      // readiness-ranked chunk: rank r -> 15,16,14,17,... (middle-out)
      const int rk = g + 8 * s;
      const int c = (rk & 1) ? (16 + (rk >> 1)) : (15 - (rk >> 1));
      wait_flag_ge(flF + c, 2);
      wait_flag_ge(flB + c, 2);
      const int t0c = c * 16;

      // single-buffered stage of the t-pair (t0c+2jp, t0c+2jp+1)
      auto stage = [&](int jp) {
        const int t = t0c + 2 * jp + tt0;
        const unsigned short* src = x + ((size_t)(b0 + row0) * T_ + t) * 640;
        unsigned short* dst = dtile + (size_t)(tt0 * 16 + row0) * 648;
        // x_left [0,256) and x_right [384,640): verbatim copy
        *(short8*)(dst + ssub * 8) = *(const short8*)(src + ssub * 8);
        *(short8*)(dst + 128 + ssub * 8) = *(const short8*)(src + 128 + ssub * 8);
        *(short8*)(dst + 384 + ssub * 8) = *(const short8*)(src + 384 + ssub * 8);
        *(short8*)(dst + 512 + ssub * 8) = *(const short8*)(src + 512 + ssub * 8);
        // e_cur middle [256,384): gather from emb with the swizzle the
        // kt=8..11 fragment reads expect: mid[r][s][l15] =
        //   e[b0+l15][16*(r&7)+8*(r>>3)+4s .. +4)
        const int er = idxC[(b0 + ssub) * T_ + t];
        const float* ep = emb + (size_t)er * E_ + f0;
        float4v e0 = *(const float4v*)ep;
        float4v e1 = *(const float4v*)(ep + 4);
        *(uint2v*)(dst + 256 + 4 * ssub) =
            (uint2v){pkbf(e0[0], e0[1]), pkbf(e0[2], e0[3])};
        *(uint2v*)(dst + 320 + 4 * ssub) =
            (uint2v){pkbf(e1[0], e1[1]), pkbf(e1[2], e1[3])};
      };

#pragma unroll 1
      for (int jp = 0; jp < 8; ++jp) {
        __syncthreads();  // prior compute reads done before overwrite
        stage(jp);
        __syncthreads();
        float4v acc0 = (float4v){0.f, 0.f, 0.f, 0.f};
        float4v acc1 = acc0;
#pragma unroll
        for (int kt = 0; kt < 20; ++kt) {
          int rrow, so1, so2;
          if (kt < 8) {
            rrow = 2 * kt + (q >> 1);
            so1 = 128 * (q & 1) + 4 * l15;
            so2 = so1 + 64;
          } else if (kt < 12) {
            rrow = 2 * (kt - 8) + (q >> 1) + 8 * (q & 1);
            so1 = 256 + 4 * l15;
            so2 = 320 + 4 * l15;
          } else {
            rrow = 2 * (kt - 12) + (q >> 1);
            so1 = 384 + 128 * (q & 1) + 4 * l15;
            so2 = so1 + 64;
          }
          const unsigned short* r0p = dtile + (size_t)rrow * 648;
          const unsigned short* r1p = r0p + 16 * 648;
          uint2v a1 = *(const uint2v*)(r0p + so1);
          uint2v a2 = *(const uint2v*)(r0p + so2);
          uint2v b1 = *(const uint2v*)(r1p + so1);
          uint2v b2 = *(const uint2v*)(r1p + so2);
          union { unsigned u[4]; short8 s8; } cva, cvb;
          cva.u[0] = a1.x; cva.u[1] = a1.y; cva.u[2] = a2.x; cva.u[3] = a2.y;
          cvb.u[0] = b1.x; cvb.u[1] = b1.y; cvb.u[2] = b2.x; cvb.u[3] = b2.y;
          acc0 = __builtin_amdgcn_mfma_f32_16x16x32_bf16(wfr[kt], cva.s8,
                                                         acc0, 0, 0, 0);
          acc1 = __builtin_amdgcn_mfma_f32_16x16x32_bf16(wfr[kt], cvb.s8,
                                                         acc1, 0, 0, 0);
        }
#pragma unroll
        for (int i = 0; i < 4; ++i)
          mx[i] = fmaxf(fmaxf(mx[i], acc0[i]), acc1[i]);  // pre-activation max
      }
    }
#pragma unroll
    for (int i = 0; i < 4; ++i)
      atomicMax(pooled + (b0 + l15) * C_ + 16 * w + 4 * q + i,
                enc_f(fast_tanh(mx[i] + bv[i])));
  }
}

// ---------------------------------------------------------------------------
// dense: out = sigmoid(pooled @ Wd + bd)  [256,128]@[128,2]
// ---------------------------------------------------------------------------
__global__ __launch_bounds__(64) void dense_kernel(
    const unsigned int* __restrict__ pooled, const float* __restrict__ Wd,
    const float* __restrict__ bd, float* __restrict__ out) {
  int b = blockIdx.x * 64 + threadIdx.x;
  float s0 = bd[0], s1 = bd[1];
#pragma unroll 4
  for (int c = 0; c < C_; ++c) {
    float f = dec_f(pooled[b * C_ + c]);
    s0 += f * Wd[c * 2 + 0];
    s1 += f * Wd[c * 2 + 1];
  }
  out[b * 2 + 0] = 1.f / (1.f + __expf(-s0));
  out[b * 2 + 1] = 1.f / (1.f + __expf(-s1));
}

// ---------------------------------------------------------------------------
extern "C" void kernel_launch(void* const* d_in, const int* in_sizes, int n_in,
                              void* d_out, int out_size, void* d_ws, size_t ws_size,
                              hipStream_t stream) {
  const int* idxC = (const int*)d_in[0];
  const int* idxL = (const int*)d_in[1];
  const int* idxR = (const int*)d_in[2];
  const float* emb = (const float*)d_in[3];
  const float* Wf = (const float*)d_in[4];
  const float* Uf = (const float*)d_in[5];
  const float* bf_ = (const float*)d_in[6];
  const float* Wb = (const float*)d_in[7];
  const float* Ub = (const float*)d_in[8];
  const float* bb_ = (const float*)d_in[9];
  const float* Wc = (const float*)d_in[10];
  const float* bc = (const float*)d_in[11];
  const float* Wd = (const float*)d_in[12];
  const float* bd = (const float*)d_in[13];

  char* ws = (char*)d_ws;
  unsigned short* x = (unsigned short*)ws;                          // 167,772,160 B
  unsigned int* pooled = (unsigned int*)(ws + 167772160);           //     131,072 B
  unsigned short* WfT = (unsigned short*)(ws + 167903232);          //      65,536 B
  unsigned short* WbT = WfT + 256 * 128;
  unsigned short* WcT = WbT + 256 * 128;
  unsigned short* UfT = WcT + 128 * 640;
  unsigned short* UbT = UfT + 256 * 256;
  int* flags = (int*)(ws + 168460288);                              //       4,096 B

  prep_kernel<<<64, 256, 0, stream>>>(Wf, Wb, Wc, Uf, Ub, WfT, WbT, WcT, UfT,
                                      UbT, pooled, flags);
  fused_kernel<<<1184, 512, 41472, stream>>>(idxL, idxR, idxC, emb, WfT,
                                             WbT, bf_, bb_, UfT, UbT, WcT,
                                             bc, x, pooled, flags);
  dense_kernel<<<4, 64, 0, stream>>>(pooled, Wd, bd, (float*)d_out);
}

// Round 8
// 544.231 us; speedup vs baseline: 2.6340x; 2.6340x over previous
//
#include <hip/hip_runtime.h>
#include <hip/hip_bf16.h>

// RCNN: bidirectional simple-RNN + conv1x1 + global max pool + dense sigmoid
// B=256 T=512 V=50000 E=128 H=256 C=128
//
// Round-22 = R19 (best verified: 546 total / 462 fused) + 2 blocks/CU via
// LDS reduction ONLY.
//  - R21 post-mortem: __launch_bounds__(512,4) forced VGPR 96->64 ->
//    massive scratch spills (FETCH 222->687 MB) -> 3x slowdown. The
//    occupancy mechanism was wrong, not the theory.
//  - R22: launch_bounds stays (512,1) (R19's bodies compile at 96 VGPR,
//    which already permits 4 waves/SIMD). Convpool tile single-buffered
//    (verified in R21: passed, absmax 0.00195): dynamic LDS 82,944 ->
//    41,472 B. Per block 17,920 + 41,472 = 59,392 B -> hardware gives
//    2 blocks/CU naturally. RNN chains get co-resident partner blocks
//    (producers) whose issue streams hide the ~60% exposed latency per
//    step (m114: MFMA/VALU/LDS co-schedule across blocks).
//  - RNN body / producers / prep / dense: verbatim R19 (lagged publish,
//    flag acquire-prefetch, split accumulators, sc1 stores).

#define B_ 256
#define T_ 512
#define E_ 128
#define H_ 256
#define C_ 128

typedef __attribute__((ext_vector_type(8))) short short8;
typedef __attribute__((ext_vector_type(4))) float float4v;
typedef __attribute__((ext_vector_type(2))) unsigned int uint2v;

__device__ inline unsigned short f2bf(float f) {
  unsigned u = __float_as_uint(f);
  u += 0x7fffu + ((u >> 16) & 1u);  // RNE
  return (unsigned short)(u >> 16);
}
__device__ inline unsigned pkbf(float a, float b) {
  __hip_bfloat162 h2 = __float22bfloat162_rn(float2{a, b});
  union { __hip_bfloat162 h; unsigned u; } cv;
  cv.h = h2;
  return cv.u;
}
__device__ inline float lo16f(unsigned u) { return __uint_as_float(u << 16); }
__device__ inline float hi16f(unsigned u) { return __uint_as_float(u & 0xffff0000u); }
__device__ inline float fast_tanh(float x) {
  float e = __expf(2.f * x);                 // inf ok -> 1
  float r = __builtin_amdgcn_rcpf(e + 1.f);
  return __builtin_fmaf(-2.f, r, 1.f);
}
__device__ inline unsigned enc_f(float f) {
  unsigned u = __float_as_uint(f);
  return (u & 0x80000000u) ? ~u : (u | 0x80000000u);
}
__device__ inline float dec_f(unsigned key) {
  unsigned bits = (key & 0x80000000u) ? (key ^ 0x80000000u) : ~key;
  return __uint_as_float(bits);
}
__device__ inline void sync_lds() {
  asm volatile("s_waitcnt lgkmcnt(0)\n\ts_barrier" ::: "memory");
}

// 8-byte store coherent at agent scope (sc1: bypasses XCD L2, lands at the
// chip coherence point). vmcnt(0) after these == globally visible.
__device__ inline void st_agent(unsigned short* p, uint2v v) {
  union { uint2v v2; unsigned long long u; } cv;
  cv.v2 = v;
  __hip_atomic_store(reinterpret_cast<unsigned long long*>(p), cv.u,
                     __ATOMIC_RELAXED, __HIP_MEMORY_SCOPE_AGENT);
}

// spin until *f >= v (flags go 0 -> 1 (xw ready) -> 2 (h ready)), then one
// acquire load to invalidate this XCD's caches.
__device__ inline void wait_flag_ge(const int* f, int v) {
  if (__hip_atomic_load(f, __ATOMIC_RELAXED, __HIP_MEMORY_SCOPE_AGENT) < v) {
    while (__hip_atomic_load(f, __ATOMIC_RELAXED, __HIP_MEMORY_SCOPE_AGENT) <
           v)
      __builtin_amdgcn_s_sleep(8);
  }
  (void)__hip_atomic_load(f, __ATOMIC_ACQUIRE, __HIP_MEMORY_SCOPE_AGENT);
}

// ---------------------------------------------------------------------------
// prep: WfT/WbT:[256][128] WcT:[128][640] UfT/UbT:[256][256] (all [n][k]).
// Output-indexed loops: coalesced writes, strided reads (L1 line reuse).
// ---------------------------------------------------------------------------
__global__ __launch_bounds__(256) void prep_kernel(
    const float* __restrict__ Wf, const float* __restrict__ Wb,
    const float* __restrict__ Wc, const float* __restrict__ Uf,
    const float* __restrict__ Ub,
    unsigned short* __restrict__ WfT, unsigned short* __restrict__ WbT,
    unsigned short* __restrict__ WcT, unsigned short* __restrict__ UfT,
    unsigned short* __restrict__ UbT, unsigned int* __restrict__ pooled,
    int* __restrict__ flags) {
  int gid = blockIdx.x * 256 + threadIdx.x;
  int stride = gridDim.x * 256;
  for (int i = gid; i < 256 * 128; i += stride) {  // WfT/WbT [256][128]
    int n = i >> 7, k = i & 127;
    WfT[i] = f2bf(Wf[k * 256 + n]);
    WbT[i] = f2bf(Wb[k * 256 + n]);
  }
  for (int i = gid; i < 128 * 640; i += stride) {  // WcT [128][640]
    int n = i / 640, k = i - n * 640;
    WcT[i] = f2bf(Wc[k * 128 + n]);
  }
  for (int i = gid; i < 256 * 256; i += stride) {  // UfT/UbT [256][256]
    int n = i >> 8, k = i & 255;
    UfT[i] = f2bf(Uf[k * 256 + n]);
    UbT[i] = f2bf(Ub[k * 256 + n]);
  }
  for (int i = gid; i < B_ * C_; i += stride) pooled[i] = 0u;
  for (int i = gid; i < 1024; i += stride) flags[i] = 0;
}

// ---------------------------------------------------------------------------
// fused: rnn (blocks 0-31) + embxw producers (32-1055) + convpool (1056-1183).
// 59,392 B LDS per block (17,920 static + 41,472 dynamic) -> 2 blocks/CU
// at the natural 96-VGPR allocation (no launch-bounds coercion).
// ---------------------------------------------------------------------------
__global__ __launch_bounds__(512, 1) void fused_kernel(
    const int* __restrict__ idxL, const int* __restrict__ idxR,
    const int* __restrict__ idxC, const float* __restrict__ emb,
    const unsigned short* __restrict__ WfT,
    const unsigned short* __restrict__ WbT,
    const float* __restrict__ bfv, const float* __restrict__ bbv,
    const unsigned short* __restrict__ UfT,
    const unsigned short* __restrict__ UbT,
    const unsigned short* __restrict__ WcT, const float* __restrict__ bc,
    unsigned short* x, unsigned int* __restrict__ pooled,
    int* __restrict__ flags) {
  const int blk = blockIdx.x;
  const int tid = threadIdx.x;
  const int lane = tid & 63, q = lane >> 4, l15 = lane & 15;

  __shared__ __attribute__((aligned(16))) unsigned short hbuf[2][16][280];

  if (blk < 32) {
    // ======================= RNN (R19 body, verbatim) ======================
    const int dir = blk & 1;
    const int btile = blk >> 1;
    const int b0 = btile * 16;
    const unsigned short* __restrict__ UT = dir ? UbT : UfT;
    const int xoff = dir ? 384 : 0;
    const int tstep = dir ? -1 : 1;
    const int t0 = dir ? (T_ - 1) : 0;
    const ptrdiff_t dstep = (ptrdiff_t)tstep * 640;
    const int wv = tid >> 6;
    int* fl = flags + (dir * 16 + btile) * 32;

    unsigned short* hb0 = &hbuf[0][0][0];
    unsigned short* hb1 = &hbuf[1][0][0];
    for (int i = tid; i < 16 * 280; i += 512) hb0[i] = 0;

    short8 ufr[2][8];
#pragma unroll
    for (int mt = 0; mt < 2; ++mt)
#pragma unroll
      for (int kt = 0; kt < 8; ++kt)
        ufr[mt][kt] = *(const short8*)(UT + (32 * wv + 16 * mt + l15) * H_ +
                                       kt * 32 + q * 8);

    int lastc = dir ? 31 : 0;
    wait_flag_ge(fl + lastc, 1);  // covers prologue reads t0..t0+3
    // acquire-prefetch of the NEXT chunk's flag (consumed >=8 iters later;
    // on hit the acquire already ordered subsequent loads -> no fence).
    int fpre = __hip_atomic_load(fl + (dir ? 30 : 1), __ATOMIC_ACQUIRE,
                                 __HIP_MEMORY_SCOPE_AGENT);
    int pending = -1;  // h-chunk awaiting (lagged) publish

    unsigned short* ptrS[2];
    const unsigned short* ptrL[2];
    uint2v curA[2], curB[2], infA[2], infB[2];
#pragma unroll
    for (int mt = 0; mt < 2; ++mt) {
      unsigned short* base =
          x + (size_t)(b0 + 2 * wv + mt) * T_ * 640 + xoff + lane * 4;
      unsigned short* bt = base + (ptrdiff_t)t0 * 640;
      curA[mt] = *(const uint2v*)(bt);
      curB[mt] = *(const uint2v*)(bt + dstep);
      infA[mt] = *(const uint2v*)(bt + 2 * dstep);
      infB[mt] = *(const uint2v*)(bt + 3 * dstep);
      ptrS[mt] = bt;
      ptrL[mt] = bt + 4 * dstep;
    }

    const unsigned lrd = l15 * 280;
    const unsigned lwr = l15 * 280 + 32 * wv;

    __syncthreads();

#pragma unroll 1
    for (int p = 0; p < 256; ++p) {
      // flag for the chunk the prefetch (t +4/+5) touches
      int c = dir ? ((506 - 2 * p) >> 4) : ((2 * p + 5) >> 4);
      c = c < 0 ? 0 : (c > 31 ? 31 : c);
      if (c != lastc) {
        if (fpre < 1) wait_flag_ge(fl + c, 1);
        lastc = c;
        const int nc = c + (dir ? -1 : 1);
        fpre = (nc >= 0 && nc < 32)
                   ? __hip_atomic_load(fl + nc, __ATOMIC_ACQUIRE,
                                       __HIP_MEMORY_SCOPE_AGENT)
                   : 1;
      }
      uint2v ldA[2], ldB[2];
      if (p < 254) {
#pragma unroll
        for (int mt = 0; mt < 2; ++mt) {
          ldA[mt] = *(const uint2v*)(ptrL[mt]);
          ldB[mt] = *(const uint2v*)(ptrL[mt] + dstep);
        }
      } else {
#pragma unroll
        for (int mt = 0; mt < 2; ++mt) {
          ldA[mt] = infA[mt];
          ldB[mt] = infB[mt];
        }
      }
#pragma unroll
      for (int mt = 0; mt < 2; ++mt) ptrL[mt] += 2 * dstep;

      // ---- STEP A: read hb0, write hb1 ----
      {
        short8 afr[8];
#pragma unroll
        for (int kt = 0; kt < 8; ++kt)
          afr[kt] = *(const short8*)(hb0 + lrd + kt * 32 + q * 8);
        float4v accA[2], accB[2];
#pragma unroll
        for (int mt = 0; mt < 2; ++mt) {
          accA[mt] = (float4v){lo16f(curA[mt].x), hi16f(curA[mt].x),
                               lo16f(curA[mt].y), hi16f(curA[mt].y)};
          accB[mt] = (float4v){0.f, 0.f, 0.f, 0.f};
        }
#pragma unroll
        for (int kt = 0; kt < 4; ++kt)
#pragma unroll
          for (int mt = 0; mt < 2; ++mt) {
            accA[mt] = __builtin_amdgcn_mfma_f32_16x16x32_bf16(
                ufr[mt][kt], afr[kt], accA[mt], 0, 0, 0);
            accB[mt] = __builtin_amdgcn_mfma_f32_16x16x32_bf16(
                ufr[mt][kt + 4], afr[kt + 4], accB[mt], 0, 0, 0);
          }
#pragma unroll
        for (int mt = 0; mt < 2; ++mt) {
          float4v s = accA[mt] + accB[mt];
          uint2v hv = {pkbf(fast_tanh(s[0]), fast_tanh(s[1])),
                       pkbf(fast_tanh(s[2]), fast_tanh(s[3]))};
          *(uint2v*)(hb1 + lwr + 16 * mt + 4 * q) = hv;
          st_agent(ptrS[mt], hv);
        }
      }
      sync_lds();

      // ---- STEP B: read hb1, write hb0 ----
      {
        short8 afr[8];
#pragma unroll
        for (int kt = 0; kt < 8; ++kt)
          afr[kt] = *(const short8*)(hb1 + lrd + kt * 32 + q * 8);
        float4v accA[2], accB[2];
#pragma unroll
        for (int mt = 0; mt < 2; ++mt) {
          accA[mt] = (float4v){lo16f(curB[mt].x), hi16f(curB[mt].x),
                               lo16f(curB[mt].y), hi16f(curB[mt].y)};
          accB[mt] = (float4v){0.f, 0.f, 0.f, 0.f};
        }
#pragma unroll
        for (int kt = 0; kt < 4; ++kt)
#pragma unroll
          for (int mt = 0; mt < 2; ++mt) {
            accA[mt] = __builtin_amdgcn_mfma_f32_16x16x32_bf16(
                ufr[mt][kt], afr[kt], accA[mt], 0, 0, 0);
            accB[mt] = __builtin_amdgcn_mfma_f32_16x16x32_bf16(
                ufr[mt][kt + 4], afr[kt + 4], accB[mt], 0, 0, 0);
          }
#pragma unroll
        for (int mt = 0; mt < 2; ++mt) {
          float4v s = accA[mt] + accB[mt];
          uint2v hv = {pkbf(fast_tanh(s[0]), fast_tanh(s[1])),
                       pkbf(fast_tanh(s[2]), fast_tanh(s[3]))};
          *(uint2v*)(hb0 + lwr + 16 * mt + 4 * q) = hv;
          st_agent(ptrS[mt] + dstep, hv);
        }
      }
#pragma unroll
      for (int mt = 0; mt < 2; ++mt) {
        ptrS[mt] += 2 * dstep;
        curA[mt] = infA[mt];
        curB[mt] = infB[mt];
        infA[mt] = ldA[mt];
        infB[mt] = ldB[mt];
      }
      if (((p + 1) & 7) == 0) {
        // lagged publish: vmcnt(16) proves everything older than the newest
        // 16 mem-ops completed -- the PREVIOUS chunk's stores are >=64
        // mem-ops old, so publishing it needs no drain.
        asm volatile("s_waitcnt vmcnt(16) lgkmcnt(0)\n\ts_barrier" :::
                         "memory");
        if (tid == 0 && pending >= 0)
          __hip_atomic_store(fl + pending, 2, __ATOMIC_RELAXED,
                             __HIP_MEMORY_SCOPE_AGENT);
        pending = dir ? (32 - ((p + 1) >> 3)) : (((p + 1) >> 3) - 1);
      } else {
        sync_lds();
      }
    }
    // drain all h-stores, then publish the final pending chunk.
    asm volatile("s_waitcnt vmcnt(0)" ::: "memory");
    __syncthreads();
    if (tid == 0)
      __hip_atomic_store(fl + pending, 2, __ATOMIC_RELAXED,
                         __HIP_MEMORY_SCOPE_AGENT);
    return;
  }

  if (blk < 1056) {
    // ==================== embxw GEMM producer ====================
    const int b2 = blk - 32;
    const int z = b2 >> 5, r = b2 & 31;
    const int btile = r & 15, dirg = r >> 4;
    const int chunk = dirg ? (31 - z) : z;
    const int w8 = tid >> 6;           // 0..7
    const int g = w8 >> 2, wv = w8 & 3;
    const int t0 = chunk * 16 + g * 8;  // this wave-group's 8 t
    const int b0 = btile * 16;
    const int* __restrict__ idx = dirg ? idxR : idxL;
    const unsigned short* __restrict__ WT = dirg ? WbT : WfT;
    const float* __restrict__ bias = dirg ? bbv : bfv;

    short8 wfr[4][4];
#pragma unroll
    for (int mt = 0; mt < 4; ++mt)
#pragma unroll
      for (int kt = 0; kt < 4; ++kt)
        wfr[mt][kt] = *(const short8*)(WT + (64 * wv + 16 * mt + l15) * 128 +
                                       kt * 32 + q * 8);
    float4v bv[4];
#pragma unroll
    for (int mt = 0; mt < 4; ++mt)
      bv[mt] = *(const float4v*)(bias + 64 * wv + 16 * mt + 4 * q);

    int er[8];
#pragma unroll
    for (int j = 0; j < 8; ++j) er[j] = idx[(b0 + l15) * T_ + t0 + j];

    float4v g0[8];
#pragma unroll
    for (int kt = 0; kt < 4; ++kt) {
      const float* p8 = emb + (size_t)er[0] * E_ + kt * 32 + q * 8;
      g0[2 * kt] = *(const float4v*)p8;
      g0[2 * kt + 1] = *(const float4v*)(p8 + 4);
    }

#pragma unroll 1
    for (int j = 0; j < 8; ++j) {
      float4v gn[8];
      if (j < 7) {
#pragma unroll
        for (int kt = 0; kt < 4; ++kt) {
          const float* p8 = emb + (size_t)er[j + 1] * E_ + kt * 32 + q * 8;
          gn[2 * kt] = *(const float4v*)p8;
          gn[2 * kt + 1] = *(const float4v*)(p8 + 4);
        }
      }
      short8 efr[4];
#pragma unroll
      for (int kt = 0; kt < 4; ++kt) {
        union { unsigned u[4]; short8 s; } cv;
        cv.u[0] = pkbf(g0[2 * kt][0], g0[2 * kt][1]);
        cv.u[1] = pkbf(g0[2 * kt][2], g0[2 * kt][3]);
        cv.u[2] = pkbf(g0[2 * kt + 1][0], g0[2 * kt + 1][1]);
        cv.u[3] = pkbf(g0[2 * kt + 1][2], g0[2 * kt + 1][3]);
        efr[kt] = cv.s;
      }
      float4v acc[4];
#pragma unroll
      for (int mt = 0; mt < 4; ++mt) acc[mt] = (float4v){0.f, 0.f, 0.f, 0.f};
#pragma unroll
      for (int kt = 0; kt < 4; ++kt)
#pragma unroll
        for (int mt = 0; mt < 4; ++mt)
          acc[mt] = __builtin_amdgcn_mfma_f32_16x16x32_bf16(
              wfr[mt][kt], efr[kt], acc[mt], 0, 0, 0);
      const int t = t0 + j;
#pragma unroll
      for (int mt = 0; mt < 4; ++mt) {
        float4v v = acc[mt] + bv[mt];
        uint2v pk = {pkbf(v[0], v[1]), pkbf(v[2], v[3])};
        st_agent(x + ((size_t)(b0 + 4 * wv + mt) * T_ + t) * 640 +
                     dirg * 384 + lane * 4,
                 pk);
      }
      if (j < 7) {
#pragma unroll
        for (int kk = 0; kk < 8; ++kk) g0[kk] = gn[kk];
      }
    }
    __syncthreads();  // drains all waves' sc1 stores (vmcnt(0) before barrier)
    if (tid == 0) {
      __hip_atomic_store(flags + (dirg * 16 + btile) * 32 + chunk, 1,
                         __ATOMIC_RELAXED, __HIP_MEMORY_SCOPE_AGENT);
    }
    return;
  }

  // =================== convpool consumer (blocks 1056-1183) =================
  {
    extern __shared__ unsigned short dtile[];  // [2][16][648] = 41,472 B
    const int b2 = blk - 1056;                 // 0..127
    const int btile = b2 & 15, g = b2 >> 4;    // rank-group 0..7
    const int b0 = btile * 16;
    const int w = tid >> 6;                    // wave 0..7 -> cols [16w,16w+16)

    short8 wfr[20];
#pragma unroll
    for (int kt = 0; kt < 20; ++kt)
      wfr[kt] =
          *(const short8*)(WcT + (size_t)(16 * w + l15) * 640 + kt * 32 + q * 8);
    float4v bv = *(const float4v*)(bc + 16 * w + 4 * q);

    float4v mx = (float4v){-1e30f, -1e30f, -1e30f, -1e30f};

    const int* flF = flags + btile * 32;         // fwd  (dir=0)
    const int* flB = flags + (16 + btile) * 32;  // bwd  (dir=1)

    const int srow = tid >> 4;                   // 0..31
    const int tt0 = srow >> 4, row0 = srow & 15;
    const int ssub = tid & 15;
    const int f0 = 16 * (row0 & 7) + 8 * (row0 >> 3);  // e_cur feature base

#pragma unroll 1
    for (int s = 0; s < 4; ++s) {
      // readiness-ranked chunk: rank r -> 15,16,14,17,... (middle-out)
      const int rk = g + 8 * s;
      const int c = (rk & 1) ? (16 + (rk >> 1)) : (15 - (rk >> 1));
      wait_flag_ge(flF + c, 2);
      wait_flag_ge(flB + c, 2);
      const int t0c = c * 16;

      // single-buffered stage of the t-pair (t0c+2jp, t0c+2jp+1)
      auto stage = [&](int jp) {
        const int t = t0c + 2 * jp + tt0;
        const unsigned short* src = x + ((size_t)(b0 + row0) * T_ + t) * 640;
        unsigned short* dst = dtile + (size_t)(tt0 * 16 + row0) * 648;
        // x_left [0,256) and x_right [384,640): verbatim copy
        *(short8*)(dst + ssub * 8) = *(const short8*)(src + ssub * 8);
        *(short8*)(dst + 128 + ssub * 8) = *(const short8*)(src + 128 + ssub * 8);
        *(short8*)(dst + 384 + ssub * 8) = *(const short8*)(src + 384 + ssub * 8);
        *(short8*)(dst + 512 + ssub * 8) = *(const short8*)(src + 512 + ssub * 8);
        // e_cur middle [256,384): gather from emb with the swizzle the
        // kt=8..11 fragment reads expect: mid[r][s][l15] =
        //   e[b0+l15][16*(r&7)+8*(r>>3)+4s .. +4)
        const int er = idxC[(b0 + ssub) * T_ + t];
        const float* ep = emb + (size_t)er * E_ + f0;
        float4v e0 = *(const float4v*)ep;
        float4v e1 = *(const float4v*)(ep + 4);
        *(uint2v*)(dst + 256 + 4 * ssub) =
            (uint2v){pkbf(e0[0], e0[1]), pkbf(e0[2], e0[3])};
        *(uint2v*)(dst + 320 + 4 * ssub) =
            (uint2v){pkbf(e1[0], e1[1]), pkbf(e1[2], e1[3])};
      };

#pragma unroll 1
      for (int jp = 0; jp < 8; ++jp) {
        __syncthreads();  // prior compute reads done before overwrite
        stage(jp);
        __syncthreads();
        float4v acc0 = (float4v){0.f, 0.f, 0.f, 0.f};
        float4v acc1 = acc0;
#pragma unroll
        for (int kt = 0; kt < 20; ++kt) {
          int rrow, so1, so2;
          if (kt < 8) {
            rrow = 2 * kt + (q >> 1);
            so1 = 128 * (q & 1) + 4 * l15;
            so2 = so1 + 64;
          } else if (kt < 12) {
            rrow = 2 * (kt - 8) + (q >> 1) + 8 * (q & 1);
            so1 = 256 + 4 * l15;
            so2 = 320 + 4 * l15;
          } else {
            rrow = 2 * (kt - 12) + (q >> 1);
            so1 = 384 + 128 * (q & 1) + 4 * l15;
            so2 = so1 + 64;
          }
          const unsigned short* r0p = dtile + (size_t)rrow * 648;
          const unsigned short* r1p = r0p + 16 * 648;
          uint2v a1 = *(const uint2v*)(r0p + so1);
          uint2v a2 = *(const uint2v*)(r0p + so2);
          uint2v b1 = *(const uint2v*)(r1p + so1);
          uint2v b2 = *(const uint2v*)(r1p + so2);
          union { unsigned u[4]; short8 s8; } cva, cvb;
          cva.u[0] = a1.x; cva.u[1] = a1.y; cva.u[2] = a2.x; cva.u[3] = a2.y;
          cvb.u[0] = b1.x; cvb.u[1] = b1.y; cvb.u[2] = b2.x; cvb.u[3] = b2.y;
          acc0 = __builtin_amdgcn_mfma_f32_16x16x32_bf16(wfr[kt], cva.s8,
                                                         acc0, 0, 0, 0);
          acc1 = __builtin_amdgcn_mfma_f32_16x16x32_bf16(wfr[kt], cvb.s8,
                                                         acc1, 0, 0, 0);
        }
#pragma unroll
        for (int i = 0; i < 4; ++i)
          mx[i] = fmaxf(fmaxf(mx[i], acc0[i]), acc1[i]);  // pre-activation max
      }
    }
#pragma unroll
    for (int i = 0; i < 4; ++i)
      atomicMax(pooled + (b0 + l15) * C_ + 16 * w + 4 * q + i,
                enc_f(fast_tanh(mx[i] + bv[i])));
  }
}

// ---------------------------------------------------------------------------
// dense: out = sigmoid(pooled @ Wd + bd)  [256,128]@[128,2]
// ---------------------------------------------------------------------------
__global__ __launch_bounds__(64) void dense_kernel(
    const unsigned int* __restrict__ pooled, const float* __restrict__ Wd,
    const float* __restrict__ bd, float* __restrict__ out) {
  int b = blockIdx.x * 64 + threadIdx.x;
  float s0 = bd[0], s1 = bd[1];
#pragma unroll 4
  for (int c = 0; c < C_; ++c) {
    float f = dec_f(pooled[b * C_ + c]);
    s0 += f * Wd[c * 2 + 0];
    s1 += f * Wd[c * 2 + 1];
  }
  out[b * 2 + 0] = 1.f / (1.f + __expf(-s0));
  out[b * 2 + 1] = 1.f / (1.f + __expf(-s1));
}

// ---------------------------------------------------------------------------
extern "C" void kernel_launch(void* const* d_in, const int* in_sizes, int n_in,
                              void* d_out, int out_size, void* d_ws, size_t ws_size,
                              hipStream_t stream) {
  const int* idxC = (const int*)d_in[0];
  const int* idxL = (const int*)d_in[1];
  const int* idxR = (const int*)d_in[2];
  const float* emb = (const float*)d_in[3];
  const float* Wf = (const float*)d_in[4];
  const float* Uf = (const float*)d_in[5];
  const float* bf_ = (const float*)d_in[6];
  const float* Wb = (const float*)d_in[7];
  const float* Ub = (const float*)d_in[8];
  const float* bb_ = (const float*)d_in[9];
  const float* Wc = (const float*)d_in[10];
  const float* bc = (const float*)d_in[11];
  const float* Wd = (const float*)d_in[12];
  const float* bd = (const float*)d_in[13];

  char* ws = (char*)d_ws;
  unsigned short* x = (unsigned short*)ws;                          // 167,772,160 B
  unsigned int* pooled = (unsigned int*)(ws + 167772160);           //     131,072 B
  unsigned short* WfT = (unsigned short*)(ws + 167903232);          //      65,536 B
  unsigned short* WbT = WfT + 256 * 128;
  unsigned short* WcT = WbT + 256 * 128;
  unsigned short* UfT = WcT + 128 * 640;
  unsigned short* UbT = UfT + 256 * 256;
  int* flags = (int*)(ws + 168460288);                              //       4,096 B

  prep_kernel<<<64, 256, 0, stream>>>(Wf, Wb, Wc, Uf, Ub, WfT, WbT, WcT, UfT,
                                      UbT, pooled, flags);
  fused_kernel<<<1184, 512, 41472, stream>>>(idxL, idxR, idxC, emb, WfT,
                                             WbT, bf_, bb_, UfT, UbT, WcT,
                                             bc, x, pooled, flags);
  dense_kernel<<<4, 64, 0, stream>>>(pooled, Wd, bd, (float*)d_out);
}

// Round 9
// 543.144 us; speedup vs baseline: 2.6392x; 1.0020x over previous
//
#include <hip/hip_runtime.h>
#include <hip/hip_bf16.h>

// RCNN: bidirectional simple-RNN + conv1x1 + global max pool + dense sigmoid
// B=256 T=512 V=50000 E=128 H=256 C=128
//
// Round-23 = R22 (544 total / 460 fused) minus the prep kernel.
// R16-R22 established the fused kernel is at its structural floor (~460 us:
// RNN serial dependency chain, unaffected by occupancy/LDS/publish tuning).
// R23 attacks the ~84 us OUTSIDE fused:
//  - prep kernel deleted. Each role self-converts its weight fragments in
//    its prologue, reading the ORIGINAL f32 arrays with the composed
//    (transpose o fragment) index map -- numerically identical to prep's
//    f2bf. All conversions are latency-hidden (RNN: behind chunk-0 flag
//    wait; producers: before cold emb gathers; convpool: behind first flag
//    wait). Weight arrays are L3-resident after first touch.
//  - flags/pooled zeroing via hipMemsetAsync (stream-ordered; pooled=0 is
//    below all enc_f keys since every key > 0).
//  - one fewer launch + one fewer inter-kernel drain.
//  - fused bodies verbatim R22 (RNN w/ lagged publish + flag prefetch +
//    split accumulators + sc1 stores; producers; single-buffered convpool
//    -> 2 blocks/CU possible; dense 4x64).

#define B_ 256
#define T_ 512
#define E_ 128
#define H_ 256
#define C_ 128

typedef __attribute__((ext_vector_type(8))) short short8;
typedef __attribute__((ext_vector_type(4))) float float4v;
typedef __attribute__((ext_vector_type(2))) unsigned int uint2v;

__device__ inline unsigned short f2bf(float f) {
  unsigned u = __float_as_uint(f);
  u += 0x7fffu + ((u >> 16) & 1u);  // RNE
  return (unsigned short)(u >> 16);
}
__device__ inline unsigned pkbf(float a, float b) {
  __hip_bfloat162 h2 = __float22bfloat162_rn(float2{a, b});
  union { __hip_bfloat162 h; unsigned u; } cv;
  cv.h = h2;
  return cv.u;
}
__device__ inline float lo16f(unsigned u) { return __uint_as_float(u << 16); }
__device__ inline float hi16f(unsigned u) { return __uint_as_float(u & 0xffff0000u); }
__device__ inline float fast_tanh(float x) {
  float e = __expf(2.f * x);                 // inf ok -> 1
  float r = __builtin_amdgcn_rcpf(e + 1.f);
  return __builtin_fmaf(-2.f, r, 1.f);
}
__device__ inline unsigned enc_f(float f) {
  unsigned u = __float_as_uint(f);
  return (u & 0x80000000u) ? ~u : (u | 0x80000000u);
}
__device__ inline float dec_f(unsigned key) {
  unsigned bits = (key & 0x80000000u) ? (key ^ 0x80000000u) : ~key;
  return __uint_as_float(bits);
}
__device__ inline void sync_lds() {
  asm volatile("s_waitcnt lgkmcnt(0)\n\ts_barrier" ::: "memory");
}

// 8-byte store coherent at agent scope (sc1: bypasses XCD L2, lands at the
// chip coherence point). vmcnt(0) after these == globally visible.
__device__ inline void st_agent(unsigned short* p, uint2v v) {
  union { uint2v v2; unsigned long long u; } cv;
  cv.v2 = v;
  __hip_atomic_store(reinterpret_cast<unsigned long long*>(p), cv.u,
                     __ATOMIC_RELAXED, __HIP_MEMORY_SCOPE_AGENT);
}

// spin until *f >= v (flags go 0 -> 1 (xw ready) -> 2 (h ready)), then one
// acquire load to invalidate this XCD's caches.
__device__ inline void wait_flag_ge(const int* f, int v) {
  if (__hip_atomic_load(f, __ATOMIC_RELAXED, __HIP_MEMORY_SCOPE_AGENT) < v) {
    while (__hip_atomic_load(f, __ATOMIC_RELAXED, __HIP_MEMORY_SCOPE_AGENT) <
           v)
      __builtin_amdgcn_s_sleep(8);
  }
  (void)__hip_atomic_load(f, __ATOMIC_ACQUIRE, __HIP_MEMORY_SCOPE_AGENT);
}

// ---------------------------------------------------------------------------
// fused: rnn (blocks 0-31) + embxw producers (32-1055) + convpool (1056-1183).
// 59,392 B LDS per block (17,920 static + 41,472 dynamic) -> 2 blocks/CU.
// ---------------------------------------------------------------------------
__global__ __launch_bounds__(512, 1) void fused_kernel(
    const int* __restrict__ idxL, const int* __restrict__ idxR,
    const int* __restrict__ idxC, const float* __restrict__ emb,
    const float* __restrict__ Wf, const float* __restrict__ Wb,
    const float* __restrict__ bfv, const float* __restrict__ bbv,
    const float* __restrict__ Uf, const float* __restrict__ Ub,
    const float* __restrict__ Wc, const float* __restrict__ bc,
    unsigned short* x, unsigned int* __restrict__ pooled,
    int* __restrict__ flags) {
  const int blk = blockIdx.x;
  const int tid = threadIdx.x;
  const int lane = tid & 63, q = lane >> 4, l15 = lane & 15;

  __shared__ __attribute__((aligned(16))) unsigned short hbuf[2][16][280];

  if (blk < 32) {
    // ======================= RNN (R19/R22 body) ============================
    const int dir = blk & 1;
    const int btile = blk >> 1;
    const int b0 = btile * 16;
    const float* __restrict__ Usrc = dir ? Ub : Uf;  // [256][256] k-major
    const int xoff = dir ? 384 : 0;
    const int tstep = dir ? -1 : 1;
    const int t0 = dir ? (T_ - 1) : 0;
    const ptrdiff_t dstep = (ptrdiff_t)tstep * 640;
    const int wv = tid >> 6;
    int* fl = flags + (dir * 16 + btile) * 32;

    unsigned short* hb0 = &hbuf[0][0][0];
    unsigned short* hb1 = &hbuf[1][0][0];
    for (int i = tid; i < 16 * 280; i += 512) hb0[i] = 0;

    // self-convert U fragments: ufr[mt][kt][e] = bf16(U[k][n]),
    // k = kt*32 + q*8 + e, n = 32*wv + 16*mt + l15  (U row-major [k][n])
    short8 ufr[2][8];
#pragma unroll
    for (int mt = 0; mt < 2; ++mt) {
      const int n = 32 * wv + 16 * mt + l15;
#pragma unroll
      for (int kt = 0; kt < 8; ++kt) {
        union { unsigned short us[8]; short8 s; } cv;
#pragma unroll
        for (int e = 0; e < 8; ++e)
          cv.us[e] = f2bf(Usrc[(kt * 32 + q * 8 + e) * H_ + n]);
        ufr[mt][kt] = cv.s;
      }
    }

    int lastc = dir ? 31 : 0;
    wait_flag_ge(fl + lastc, 1);  // covers prologue reads t0..t0+3
    // acquire-prefetch of the NEXT chunk's flag (consumed >=8 iters later;
    // on hit the acquire already ordered subsequent loads -> no fence).
    int fpre = __hip_atomic_load(fl + (dir ? 30 : 1), __ATOMIC_ACQUIRE,
                                 __HIP_MEMORY_SCOPE_AGENT);
    int pending = -1;  // h-chunk awaiting (lagged) publish

    unsigned short* ptrS[2];
    const unsigned short* ptrL[2];
    uint2v curA[2], curB[2], infA[2], infB[2];
#pragma unroll
    for (int mt = 0; mt < 2; ++mt) {
      unsigned short* base =
          x + (size_t)(b0 + 2 * wv + mt) * T_ * 640 + xoff + lane * 4;
      unsigned short* bt = base + (ptrdiff_t)t0 * 640;
      curA[mt] = *(const uint2v*)(bt);
      curB[mt] = *(const uint2v*)(bt + dstep);
      infA[mt] = *(const uint2v*)(bt + 2 * dstep);
      infB[mt] = *(const uint2v*)(bt + 3 * dstep);
      ptrS[mt] = bt;
      ptrL[mt] = bt + 4 * dstep;
    }

    const unsigned lrd = l15 * 280;
    const unsigned lwr = l15 * 280 + 32 * wv;

    __syncthreads();

#pragma unroll 1
    for (int p = 0; p < 256; ++p) {
      // flag for the chunk the prefetch (t +4/+5) touches
      int c = dir ? ((506 - 2 * p) >> 4) : ((2 * p + 5) >> 4);
      c = c < 0 ? 0 : (c > 31 ? 31 : c);
      if (c != lastc) {
        if (fpre < 1) wait_flag_ge(fl + c, 1);
        lastc = c;
        const int nc = c + (dir ? -1 : 1);
        fpre = (nc >= 0 && nc < 32)
                   ? __hip_atomic_load(fl + nc, __ATOMIC_ACQUIRE,
                                       __HIP_MEMORY_SCOPE_AGENT)
                   : 1;
      }
      uint2v ldA[2], ldB[2];
      if (p < 254) {
#pragma unroll
        for (int mt = 0; mt < 2; ++mt) {
          ldA[mt] = *(const uint2v*)(ptrL[mt]);
          ldB[mt] = *(const uint2v*)(ptrL[mt] + dstep);
        }
      } else {
#pragma unroll
        for (int mt = 0; mt < 2; ++mt) {
          ldA[mt] = infA[mt];
          ldB[mt] = infB[mt];
        }
      }
#pragma unroll
      for (int mt = 0; mt < 2; ++mt) ptrL[mt] += 2 * dstep;

      // ---- STEP A: read hb0, write hb1 ----
      {
        short8 afr[8];
#pragma unroll
        for (int kt = 0; kt < 8; ++kt)
          afr[kt] = *(const short8*)(hb0 + lrd + kt * 32 + q * 8);
        float4v accA[2], accB[2];
#pragma unroll
        for (int mt = 0; mt < 2; ++mt) {
          accA[mt] = (float4v){lo16f(curA[mt].x), hi16f(curA[mt].x),
                               lo16f(curA[mt].y), hi16f(curA[mt].y)};
          accB[mt] = (float4v){0.f, 0.f, 0.f, 0.f};
        }
#pragma unroll
        for (int kt = 0; kt < 4; ++kt)
#pragma unroll
          for (int mt = 0; mt < 2; ++mt) {
            accA[mt] = __builtin_amdgcn_mfma_f32_16x16x32_bf16(
                ufr[mt][kt], afr[kt], accA[mt], 0, 0, 0);
            accB[mt] = __builtin_amdgcn_mfma_f32_16x16x32_bf16(
                ufr[mt][kt + 4], afr[kt + 4], accB[mt], 0, 0, 0);
          }
#pragma unroll
        for (int mt = 0; mt < 2; ++mt) {
          float4v s = accA[mt] + accB[mt];
          uint2v hv = {pkbf(fast_tanh(s[0]), fast_tanh(s[1])),
                       pkbf(fast_tanh(s[2]), fast_tanh(s[3]))};
          *(uint2v*)(hb1 + lwr + 16 * mt + 4 * q) = hv;
          st_agent(ptrS[mt], hv);
        }
      }
      sync_lds();

      // ---- STEP B: read hb1, write hb0 ----
      {
        short8 afr[8];
#pragma unroll
        for (int kt = 0; kt < 8; ++kt)
          afr[kt] = *(const short8*)(hb1 + lrd + kt * 32 + q * 8);
        float4v accA[2], accB[2];
#pragma unroll
        for (int mt = 0; mt < 2; ++mt) {
          accA[mt] = (float4v){lo16f(curB[mt].x), hi16f(curB[mt].x),
                               lo16f(curB[mt].y), hi16f(curB[mt].y)};
          accB[mt] = (float4v){0.f, 0.f, 0.f, 0.f};
        }
#pragma unroll
        for (int kt = 0; kt < 4; ++kt)
#pragma unroll
          for (int mt = 0; mt < 2; ++mt) {
            accA[mt] = __builtin_amdgcn_mfma_f32_16x16x32_bf16(
                ufr[mt][kt], afr[kt], accA[mt], 0, 0, 0);
            accB[mt] = __builtin_amdgcn_mfma_f32_16x16x32_bf16(
                ufr[mt][kt + 4], afr[kt + 4], accB[mt], 0, 0, 0);
          }
#pragma unroll
        for (int mt = 0; mt < 2; ++mt) {
          float4v s = accA[mt] + accB[mt];
          uint2v hv = {pkbf(fast_tanh(s[0]), fast_tanh(s[1])),
                       pkbf(fast_tanh(s[2]), fast_tanh(s[3]))};
          *(uint2v*)(hb0 + lwr + 16 * mt + 4 * q) = hv;
          st_agent(ptrS[mt] + dstep, hv);
        }
      }
#pragma unroll
      for (int mt = 0; mt < 2; ++mt) {
        ptrS[mt] += 2 * dstep;
        curA[mt] = infA[mt];
        curB[mt] = infB[mt];
        infA[mt] = ldA[mt];
        infB[mt] = ldB[mt];
      }
      if (((p + 1) & 7) == 0) {
        // lagged publish: vmcnt(16) proves everything older than the newest
        // 16 mem-ops completed -- the PREVIOUS chunk's stores are >=64
        // mem-ops old, so publishing it needs no drain.
        asm volatile("s_waitcnt vmcnt(16) lgkmcnt(0)\n\ts_barrier" :::
                         "memory");
        if (tid == 0 && pending >= 0)
          __hip_atomic_store(fl + pending, 2, __ATOMIC_RELAXED,
                             __HIP_MEMORY_SCOPE_AGENT);
        pending = dir ? (32 - ((p + 1) >> 3)) : (((p + 1) >> 3) - 1);
      } else {
        sync_lds();
      }
    }
    // drain all h-stores, then publish the final pending chunk.
    asm volatile("s_waitcnt vmcnt(0)" ::: "memory");
    __syncthreads();
    if (tid == 0)
      __hip_atomic_store(fl + pending, 2, __ATOMIC_RELAXED,
                         __HIP_MEMORY_SCOPE_AGENT);
    return;
  }

  if (blk < 1056) {
    // ==================== embxw GEMM producer ====================
    const int b2 = blk - 32;
    const int z = b2 >> 5, r = b2 & 31;
    const int btile = r & 15, dirg = r >> 4;
    const int chunk = dirg ? (31 - z) : z;
    const int w8 = tid >> 6;           // 0..7
    const int g = w8 >> 2, wv = w8 & 3;
    const int t0 = chunk * 16 + g * 8;  // this wave-group's 8 t
    const int b0 = btile * 16;
    const int* __restrict__ idx = dirg ? idxR : idxL;
    const float* __restrict__ Wsrc = dirg ? Wb : Wf;  // [128][256] k-major
    const float* __restrict__ bias = dirg ? bbv : bfv;

    // self-convert W fragments: wfr[mt][kt][e] = bf16(W[k][n]),
    // k = kt*32 + q*8 + e (<128), n = 64*wv + 16*mt + l15
    short8 wfr[4][4];
#pragma unroll
    for (int mt = 0; mt < 4; ++mt) {
      const int n = 64 * wv + 16 * mt + l15;
#pragma unroll
      for (int kt = 0; kt < 4; ++kt) {
        union { unsigned short us[8]; short8 s; } cv;
#pragma unroll
        for (int e = 0; e < 8; ++e)
          cv.us[e] = f2bf(Wsrc[(kt * 32 + q * 8 + e) * H_ + n]);
        wfr[mt][kt] = cv.s;
      }
    }
    float4v bv[4];
#pragma unroll
    for (int mt = 0; mt < 4; ++mt)
      bv[mt] = *(const float4v*)(bias + 64 * wv + 16 * mt + 4 * q);

    int er[8];
#pragma unroll
    for (int j = 0; j < 8; ++j) er[j] = idx[(b0 + l15) * T_ + t0 + j];

    float4v g0[8];
#pragma unroll
    for (int kt = 0; kt < 4; ++kt) {
      const float* p8 = emb + (size_t)er[0] * E_ + kt * 32 + q * 8;
      g0[2 * kt] = *(const float4v*)p8;
      g0[2 * kt + 1] = *(const float4v*)(p8 + 4);
    }

#pragma unroll 1
    for (int j = 0; j < 8; ++j) {
      float4v gn[8];
      if (j < 7) {
#pragma unroll
        for (int kt = 0; kt < 4; ++kt) {
          const float* p8 = emb + (size_t)er[j + 1] * E_ + kt * 32 + q * 8;
          gn[2 * kt] = *(const float4v*)p8;
          gn[2 * kt + 1] = *(const float4v*)(p8 + 4);
        }
      }
      short8 efr[4];
#pragma unroll
      for (int kt = 0; kt < 4; ++kt) {
        union { unsigned u[4]; short8 s; } cv;
        cv.u[0] = pkbf(g0[2 * kt][0], g0[2 * kt][1]);
        cv.u[1] = pkbf(g0[2 * kt][2], g0[2 * kt][3]);
        cv.u[2] = pkbf(g0[2 * kt + 1][0], g0[2 * kt + 1][1]);
        cv.u[3] = pkbf(g0[2 * kt + 1][2], g0[2 * kt + 1][3]);
        efr[kt] = cv.s;
      }
      float4v acc[4];
#pragma unroll
      for (int mt = 0; mt < 4; ++mt) acc[mt] = (float4v){0.f, 0.f, 0.f, 0.f};
#pragma unroll
      for (int kt = 0; kt < 4; ++kt)
#pragma unroll
        for (int mt = 0; mt < 4; ++mt)
          acc[mt] = __builtin_amdgcn_mfma_f32_16x16x32_bf16(
              wfr[mt][kt], efr[kt], acc[mt], 0, 0, 0);
      const int t = t0 + j;
#pragma unroll
      for (int mt = 0; mt < 4; ++mt) {
        float4v v = acc[mt] + bv[mt];
        uint2v pk = {pkbf(v[0], v[1]), pkbf(v[2], v[3])};
        st_agent(x + ((size_t)(b0 + 4 * wv + mt) * T_ + t) * 640 +
                     dirg * 384 + lane * 4,
                 pk);
      }
      if (j < 7) {
#pragma unroll
        for (int kk = 0; kk < 8; ++kk) g0[kk] = gn[kk];
      }
    }
    __syncthreads();  // drains all waves' sc1 stores (vmcnt(0) before barrier)
    if (tid == 0) {
      __hip_atomic_store(flags + (dirg * 16 + btile) * 32 + chunk, 1,
                         __ATOMIC_RELAXED, __HIP_MEMORY_SCOPE_AGENT);
    }
    return;
  }

  // =================== convpool consumer (blocks 1056-1183) =================
  {
    extern __shared__ unsigned short dtile[];  // [2][16][648] = 41,472 B
    const int b2 = blk - 1056;                 // 0..127
    const int btile = b2 & 15, g = b2 >> 4;    // rank-group 0..7
    const int b0 = btile * 16;
    const int w = tid >> 6;                    // wave 0..7 -> cols [16w,16w+16)

    // self-convert Wc fragments: wfr[kt][e] = bf16(Wc[k][n]),
    // k = kt*32 + q*8 + e (<640), n = 16*w + l15   (Wc row-major [640][128])
    short8 wfr[20];
    {
      const int n = 16 * w + l15;
#pragma unroll
      for (int kt = 0; kt < 20; ++kt) {
        union { unsigned short us[8]; short8 s; } cv;
#pragma unroll
        for (int e = 0; e < 8; ++e)
          cv.us[e] = f2bf(Wc[(size_t)(kt * 32 + q * 8 + e) * C_ + n]);
        wfr[kt] = cv.s;
      }
    }
    float4v bv = *(const float4v*)(bc + 16 * w + 4 * q);

    float4v mx = (float4v){-1e30f, -1e30f, -1e30f, -1e30f};

    const int* flF = flags + btile * 32;         // fwd  (dir=0)
    const int* flB = flags + (16 + btile) * 32;  // bwd  (dir=1)

    const int srow = tid >> 4;                   // 0..31
    const int tt0 = srow >> 4, row0 = srow & 15;
    const int ssub = tid & 15;
    const int f0 = 16 * (row0 & 7) + 8 * (row0 >> 3);  // e_cur feature base

#pragma unroll 1
    for (int s = 0; s < 4; ++s) {
      // readiness-ranked chunk: rank r -> 15,16,14,17,... (middle-out)
      const int rk = g + 8 * s;
      const int c = (rk & 1) ? (16 + (rk >> 1)) : (15 - (rk >> 1));
      wait_flag_ge(flF + c, 2);
      wait_flag_ge(flB + c, 2);
      const int t0c = c * 16;

      // single-buffered stage of the t-pair (t0c+2jp, t0c+2jp+1)
      auto stage = [&](int jp) {
        const int t = t0c + 2 * jp + tt0;
        const unsigned short* src = x + ((size_t)(b0 + row0) * T_ + t) * 640;
        unsigned short* dst = dtile + (size_t)(tt0 * 16 + row0) * 648;
        // x_left [0,256) and x_right [384,640): verbatim copy
        *(short8*)(dst + ssub * 8) = *(const short8*)(src + ssub * 8);
        *(short8*)(dst + 128 + ssub * 8) = *(const short8*)(src + 128 + ssub * 8);
        *(short8*)(dst + 384 + ssub * 8) = *(const short8*)(src + 384 + ssub * 8);
        *(short8*)(dst + 512 + ssub * 8) = *(const short8*)(src + 512 + ssub * 8);
        // e_cur middle [256,384): gather from emb with the swizzle the
        // kt=8..11 fragment reads expect: mid[r][s][l15] =
        //   e[b0+l15][16*(r&7)+8*(r>>3)+4s .. +4)
        const int er = idxC[(b0 + ssub) * T_ + t];
        const float* ep = emb + (size_t)er * E_ + f0;
        float4v e0 = *(const float4v*)ep;
        float4v e1 = *(const float4v*)(ep + 4);
        *(uint2v*)(dst + 256 + 4 * ssub) =
            (uint2v){pkbf(e0[0], e0[1]), pkbf(e0[2], e0[3])};
        *(uint2v*)(dst + 320 + 4 * ssub) =
            (uint2v){pkbf(e1[0], e1[1]), pkbf(e1[2], e1[3])};
      };

#pragma unroll 1
      for (int jp = 0; jp < 8; ++jp) {
        __syncthreads();  // prior compute reads done before overwrite
        stage(jp);
        __syncthreads();
        float4v acc0 = (float4v){0.f, 0.f, 0.f, 0.f};
        float4v acc1 = acc0;
#pragma unroll
        for (int kt = 0; kt < 20; ++kt) {
          int rrow, so1, so2;
          if (kt < 8) {
            rrow = 2 * kt + (q >> 1);
            so1 = 128 * (q & 1) + 4 * l15;
            so2 = so1 + 64;
          } else if (kt < 12) {
            rrow = 2 * (kt - 8) + (q >> 1) + 8 * (q & 1);
            so1 = 256 + 4 * l15;
            so2 = 320 + 4 * l15;
          } else {
            rrow = 2 * (kt - 12) + (q >> 1);
            so1 = 384 + 128 * (q & 1) + 4 * l15;
            so2 = so1 + 64;
          }
          const unsigned short* r0p = dtile + (size_t)rrow * 648;
          const unsigned short* r1p = r0p + 16 * 648;
          uint2v a1 = *(const uint2v*)(r0p + so1);
          uint2v a2 = *(const uint2v*)(r0p + so2);
          uint2v b1 = *(const uint2v*)(r1p + so1);
          uint2v b2 = *(const uint2v*)(r1p + so2);
          union { unsigned u[4]; short8 s8; } cva, cvb;
          cva.u[0] = a1.x; cva.u[1] = a1.y; cva.u[2] = a2.x; cva.u[3] = a2.y;
          cvb.u[0] = b1.x; cvb.u[1] = b1.y; cvb.u[2] = b2.x; cvb.u[3] = b2.y;
          acc0 = __builtin_amdgcn_mfma_f32_16x16x32_bf16(wfr[kt], cva.s8,
                                                         acc0, 0, 0, 0);
          acc1 = __builtin_amdgcn_mfma_f32_16x16x32_bf16(wfr[kt], cvb.s8,
                                                         acc1, 0, 0, 0);
        }
#pragma unroll
        for (int i = 0; i < 4; ++i)
          mx[i] = fmaxf(fmaxf(mx[i], acc0[i]), acc1[i]);  // pre-activation max
      }
    }
#pragma unroll
    for (int i = 0; i < 4; ++i)
      atomicMax(pooled + (b0 + l15) * C_ + 16 * w + 4 * q + i,
                enc_f(fast_tanh(mx[i] + bv[i])));
  }
}

// ---------------------------------------------------------------------------
// dense: out = sigmoid(pooled @ Wd + bd)  [256,128]@[128,2]
// ---------------------------------------------------------------------------
__global__ __launch_bounds__(64) void dense_kernel(
    const unsigned int* __restrict__ pooled, const float* __restrict__ Wd,
    const float* __restrict__ bd, float* __restrict__ out) {
  int b = blockIdx.x * 64 + threadIdx.x;
  float s0 = bd[0], s1 = bd[1];
#pragma unroll 4
  for (int c = 0; c < C_; ++c) {
    float f = dec_f(pooled[b * C_ + c]);
    s0 += f * Wd[c * 2 + 0];
    s1 += f * Wd[c * 2 + 1];
  }
  out[b * 2 + 0] = 1.f / (1.f + __expf(-s0));
  out[b * 2 + 1] = 1.f / (1.f + __expf(-s1));
}

// ---------------------------------------------------------------------------
extern "C" void kernel_launch(void* const* d_in, const int* in_sizes, int n_in,
                              void* d_out, int out_size, void* d_ws, size_t ws_size,
                              hipStream_t stream) {
  const int* idxC = (const int*)d_in[0];
  const int* idxL = (const int*)d_in[1];
  const int* idxR = (const int*)d_in[2];
  const float* emb = (const float*)d_in[3];
  const float* Wf = (const float*)d_in[4];
  const float* Uf = (const float*)d_in[5];
  const float* bf_ = (const float*)d_in[6];
  const float* Wb = (const float*)d_in[7];
  const float* Ub = (const float*)d_in[8];
  const float* bb_ = (const float*)d_in[9];
  const float* Wc = (const float*)d_in[10];
  const float* bc = (const float*)d_in[11];
  const float* Wd = (const float*)d_in[12];
  const float* bd = (const float*)d_in[13];

  char* ws = (char*)d_ws;
  unsigned short* x = (unsigned short*)ws;                          // 167,772,160 B
  unsigned int* pooled = (unsigned int*)(ws + 167772160);           //     131,072 B
  int* flags = (int*)(ws + 167903232);                              //       4,096 B

  hipMemsetAsync(pooled, 0, B_ * C_ * 4, stream);
  hipMemsetAsync(flags, 0, 1024 * 4, stream);
  fused_kernel<<<1184, 512, 41472, stream>>>(idxL, idxR, idxC, emb, Wf, Wb,
                                             bf_, bb_, Uf, Ub, Wc, bc, x,
                                             pooled, flags);
  dense_kernel<<<4, 64, 0, stream>>>(pooled, Wd, bd, (float*)d_out);
}